// Round 6
// baseline (248.357 us; speedup 1.0000x reference)
//
#include <hip/hip_runtime.h>
#include <math.h>

#define BB 256
#define NN 65536
#define NTA 256
#define NTB 256
#define NTC 1024
#define SLICES 8
#define SLICE_ELEMS 8192       // NN / SLICES
#define SM 4096                // samples per row
#define RANKPAD 160            // sample-rank cushion (~5 sigma); fallback guards
#define CAPC 8192              // per-row candidate capacity
#define BCAP 1024              // per-block LDS candidate staging
#define CAPB 2048              // micro-band capacity
#define QMARG 2e-3f            // relative q-space margin (== validated w margin)

typedef float f32x4 __attribute__((ext_vector_type(4)));
typedef unsigned int u32x4 __attribute__((ext_vector_type(4)));

#define ONE_BITS 0x3F800000u   // bit pattern of 1.0f

// workspace layout (u32 words)
#define WS_K    0
#define WS_HI   (WS_K + BB)
#define WS_LO   (WS_HI + BB)
#define WS_CAND (WS_LO + BB)
#define WS_A    (WS_CAND + BB)
#define WS_KEYS (WS_A + BB)
#define WS_IDX  (WS_KEYS + BB * CAPC)
#define WS_WORDS ((size_t)WS_IDX + (size_t)BB * CAPC)

// Monotonic map: float order == uint order (ascending), and inverse
__device__ __forceinline__ unsigned int f2sort(float f) {
    unsigned int b = __float_as_uint(f);
    return (b & 0x80000000u) ? ~b : (b | 0x80000000u);
}
__device__ __forceinline__ float sort2f(unsigned int u) {
    unsigned int b = (u & 0x80000000u) ? (u & 0x7fffffffu) : ~u;
    return __uint_as_float(b);
}

// Bit-exact vs numpy f32 (f64 log rounded to f32) — band + fallback only.
__device__ __forceinline__ unsigned int wexact(float u, float d) {
    float t1 = u + 1e-7f;
    float t2 = (float)log((double)t1);
    float t3 = (-t2) + 1e-7f;
    float G  = -(float)log((double)t3);
    float lgD = (float)log((double)d);
    return f2sort(G + lgD);
}

// Order-equivalent fast key: w = ln(d/t3) => rank by q = d/t3 directly.
// t1 = u+1e-7 <= 1.0f always (max f32 u<1 rounds to 1.0) so t3 >= 1e-7 > 0.
__device__ __forceinline__ unsigned int qkey(float u, float d) {
    float t3 = 1e-7f - __logf(u + 1e-7f);
    float q  = d * __builtin_amdgcn_rcpf(t3);
    return f2sort(q);
}

__device__ __forceinline__ bool finite_f(float f) {
    return (__float_as_uint(f) & 0x7f800000u) != 0x7f800000u;
}

#define PASS1SEL(KKV) \
    { const int b0 = tid * 8; unsigned int cs = 0; \
      _Pragma("unroll") for (int i = 0; i < 8; i++) cs += hist[b0 + i]; \
      chunkSum[tid] = cs; } \
    __syncthreads(); \
    if (tid < 64) { \
        const int c0i = lane * 16; unsigned int s = 0; \
        _Pragma("unroll") for (int i = 0; i < 16; i++) s += chunkSum[c0i + i]; \
        unsigned int suf = s; \
        _Pragma("unroll") for (int off = 1; off < 64; off <<= 1) { \
            unsigned int tv = __shfl_down(suf, off); if (lane + off < 64) suf += tv; } \
        unsigned int above = suf - s; \
        if (suf >= (KKV) && above < (KKV)) { \
            unsigned int cum = above; \
            for (int ci = c0i + 15; ci >= c0i; ci--) { \
                unsigned int cch = chunkSum[ci]; \
                if (cum + cch >= (KKV)) { \
                    for (int b = ci * 8 + 7; ; b--) { \
                        unsigned int c2 = hist[b]; \
                        if (cum + c2 >= (KKV)) { s_sel = (unsigned int)b; s_kneed = (KKV) - cum; s_eq = c2; break; } \
                        cum += c2; } \
                    break; } \
                cum += cch; } } } \
    __syncthreads();

#define PASS2SEL(P, KN) \
    if (tid < 64) { \
        const int c0i = lane * 16; unsigned int s = 0; \
        _Pragma("unroll") for (int i = 0; i < 16; i++) s += hist[c0i + i]; \
        unsigned int suf = s; \
        _Pragma("unroll") for (int off = 1; off < 64; off <<= 1) { \
            unsigned int tv = __shfl_down(suf, off); if (lane + off < 64) suf += tv; } \
        unsigned int above = suf - s; \
        if (suf >= (KN) && above < (KN)) { \
            unsigned int cum = above; \
            for (int b = c0i + 15; ; b--) { \
                unsigned int c2 = hist[b]; \
                if (cum + c2 >= (KN)) { s_sel = ((P) << 10) | (unsigned int)b; s_kneed = (KN) - cum; s_eq = c2; break; } \
                cum += c2; } } } \
    __syncthreads();

#define PASS3SEL(P, KN) \
    if (tid < 64) { \
        const int c0i = lane * 8; unsigned int s = 0; \
        _Pragma("unroll") for (int i = 0; i < 8; i++) s += hist[c0i + i]; \
        unsigned int suf = s; \
        _Pragma("unroll") for (int off = 1; off < 64; off <<= 1) { \
            unsigned int tv = __shfl_down(suf, off); if (lane + off < 64) suf += tv; } \
        unsigned int above = suf - s; \
        if (suf >= (KN) && above < (KN)) { \
            unsigned int cum = above; \
            for (int b = c0i + 7; ; b--) { \
                unsigned int c2 = hist[b]; \
                if (cum + c2 >= (KN)) { s_sel = ((P) << 9) | (unsigned int)b; s_kneed = (KN) - cum; s_eq = c2; break; } \
                cum += c2; } } } \
    __syncthreads();

// exact r-th-largest key among skey[SM], byte-radix top-down. NT must be 256.
__device__ __forceinline__ unsigned int rankSelect(const unsigned int* skey,
        unsigned int* h, unsigned int* s_pfx, int* s_need,
        const int tid, const int lane, const int r) {
    if (tid == 0) { *s_pfx = 0u; *s_need = r; }
    __syncthreads();
    for (int shift = 24; shift >= 0; shift -= 8) {
        h[tid] = 0u;
        __syncthreads();
        const unsigned int pfx = *s_pfx;
        const int need = *s_need;
        for (int j = tid; j < SM; j += NTA) {
            const unsigned int sk = skey[j];
            if (shift == 24 || (sk >> (shift + 8)) == (pfx >> (shift + 8)))
                atomicAdd(&h[(sk >> shift) & 255u], 1u);
        }
        __syncthreads();
        if (tid < 64) {
            const int b0 = lane * 4;
            unsigned int s = h[b0] + h[b0 + 1] + h[b0 + 2] + h[b0 + 3];
            unsigned int suf = s;
#pragma unroll
            for (int off = 1; off < 64; off <<= 1) {
                unsigned int tv = __shfl_down(suf, off);
                if (lane + off < 64) suf += tv;
            }
            const unsigned int above = suf - s;
            if (suf >= (unsigned int)need && above < (unsigned int)need) {
                unsigned int cum = above;
                for (int b = b0 + 3; ; b--) {
                    const unsigned int c = h[b];
                    if (cum + c >= (unsigned int)need) {
                        *s_pfx = pfx | ((unsigned int)b << shift);
                        *s_need = need - (int)cum;
                        break;
                    }
                    cum += c;
                }
            }
        }
        __syncthreads();
    }
    return *s_pfx;
}

// ======================= kernel A: per-row pivots ==========================
__global__ __launch_bounds__(NTA)
void md_pivots(const float* __restrict__ Tt, const float* __restrict__ U,
               const float* __restrict__ D, unsigned int* __restrict__ ws,
               float* __restrict__ wout) {
    const int row = blockIdx.x;
    const int tid = threadIdx.x;
    const int lane = tid & 63;

    const float t = Tt[row];
    const float pf = (float)M_PI;
    float bbv = (pf * t) * 0.5f;
    float c0 = (float)cos((double)bbv);
    const int k = (int)(65536.0f * (1.0f - c0));
    if (tid == 0) {
        float tadj = t * 0.998f + 0.001f;
        float arg = (pf * tadj) * 0.5f;
        wout[row] = (float)(0.5 * M_PI) * (float)sin((double)arg);
        ws[WS_K + row] = (unsigned int)k;
        ((int*)ws)[WS_CAND + row] = 0;
        ((int*)ws)[WS_A + row] = 0;
    }
    if (k <= 0 || k >= NN) {
        if (tid == 0) { ws[WS_HI + row] = 0xFFFFFFFFu; ws[WS_LO + row] = 0u; }
        return;
    }

    __shared__ unsigned int skey[SM];
    __shared__ unsigned int h[256];
    __shared__ unsigned int s_pfx;
    __shared__ int s_need;

    const float* Ur = U + (size_t)row * NN;
    const float* Dr = D + (size_t)row * NN;
#pragma unroll
    for (int g = 0; g < 4; ++g) {
        const int e = (g << 10) + (tid << 2);
        float4 u4 = *(const float4*)(Ur + e);
        float4 d4 = *(const float4*)(Dr + e);
        skey[e + 0] = qkey(u4.x, d4.x);
        skey[e + 1] = qkey(u4.y, d4.y);
        skey[e + 2] = qkey(u4.z, d4.z);
        skey[e + 3] = qkey(u4.w, d4.w);
    }
    __syncthreads();

    const int rh = (k >> 4) - RANKPAD;
    const int rl = (k >> 4) + RANKPAD;
    unsigned int hi = 0xFFFFFFFFu;   // inactive: nothing definite-in
    unsigned int lo = 0u;            // inactive: everything candidate
    if (rh >= 1)  hi = rankSelect(skey, h, &s_pfx, &s_need, tid, lane, rh);
    if (rl <= SM) lo = rankSelect(skey, h, &s_pfx, &s_need, tid, lane, rl);
    if (tid == 0) { ws[WS_HI + row] = hi; ws[WS_LO + row] = lo; }
}

// ======================= kernel B: the streaming pass ======================
__global__ __launch_bounds__(NTB)
void md_stream(const float* __restrict__ U, const float* __restrict__ D,
               float* __restrict__ out, unsigned int* __restrict__ ws) {
    const int bid = blockIdx.x;
    const int row = bid >> 3;
    const int sl = bid & 7;
    const int tid = threadIdx.x;
    const int lane = tid & 63;

    const int k = (int)ws[WS_K + row];
    unsigned int* OrU = (unsigned int*)out + (size_t)row * NN + (size_t)sl * SLICE_ELEMS;
    if (k <= 0 || k >= NN) {
        const unsigned int fv = (k >= NN) ? ONE_BITS : 0u;
        u32x4 f4 = {fv, fv, fv, fv};
        for (int J = 0; J < 8; ++J)
            __builtin_nontemporal_store(f4, (u32x4*)(OrU + (J << 10) + (tid << 2)));
        return;
    }
    const unsigned int hi = ws[WS_HI + row];
    const unsigned int lo = ws[WS_LO + row];
    const float* Ur = U + (size_t)row * NN + (size_t)sl * SLICE_ELEMS;
    const float* Dr = D + (size_t)row * NN + (size_t)sl * SLICE_ELEMS;
    unsigned int* gk = ws + WS_KEYS + (size_t)row * CAPC;
    int* gi = (int*)ws + WS_IDX + (size_t)row * CAPC;
    int* gCand = (int*)ws + WS_CAND + row;
    int* gA = (int*)ws + WS_A + row;

    __shared__ unsigned int lk[BCAP];
    __shared__ int li[BCAP];
    __shared__ int s_cnt, s_base;
    if (tid == 0) s_cnt = 0;
    __syncthreads();

    int dcnt = 0;
    const int ibase = sl * SLICE_ELEMS;
#pragma unroll 2
    for (int J = 0; J < 8; ++J) {
        const int e = (J << 10) + (tid << 2);
        float4 u4 = *(const float4*)(Ur + e);
        float4 d4 = *(const float4*)(Dr + e);
        u32x4 kv;
        kv.x = qkey(u4.x, d4.x); kv.y = qkey(u4.y, d4.y);
        kv.z = qkey(u4.z, d4.z); kv.w = qkey(u4.w, d4.w);
        u32x4 m;
#define SPROC(QV, CI, MF) { const unsigned int qv = (QV); \
        const bool din = qv > hi; dcnt += (int)din; MF = din ? ONE_BITS : 0u; \
        if (!din && qv > lo) { \
            const int p = atomicAdd(&s_cnt, 1); \
            if (p < BCAP) { lk[p] = qv; li[p] = ibase + e + (CI); } \
            else { const int g = atomicAdd(gCand, 1); \
                   if (g < CAPC) { gk[g] = qv; gi[g] = ibase + e + (CI); } } } }
        SPROC(kv.x, 0, m.x)
        SPROC(kv.y, 1, m.y)
        SPROC(kv.z, 2, m.z)
        SPROC(kv.w, 3, m.w)
#undef SPROC
        *(u32x4*)(OrU + e) = m;
    }
#pragma unroll
    for (int off = 32; off >= 1; off >>= 1) dcnt += __shfl_down(dcnt, off);
    if (lane == 0 && dcnt) atomicAdd(gA, dcnt);
    __syncthreads();
    if (tid == 0) {
        int n = s_cnt; if (n > BCAP) n = BCAP;
        s_base = atomicAdd(gCand, n);
    }
    __syncthreads();
    {
        int n = s_cnt; if (n > BCAP) n = BCAP;
        for (int j = tid; j < n; j += NTB) {
            const int g = s_base + j;
            if (g < CAPC) { gk[g] = lk[j]; gi[g] = li[j]; }
        }
    }
}

// ======================= kernel C: per-row selection + fixups ==============
__global__ __launch_bounds__(NTC)
void md_select(const float* __restrict__ U, const float* __restrict__ D,
               float* __restrict__ out, unsigned int* __restrict__ ws) {
    const int row = blockIdx.x;
    const int tid = threadIdx.x;
    const int lane = tid & 63;

    const int k = (int)ws[WS_K + row];
    if (k <= 0 || k >= NN) return;
    const unsigned int kk = (unsigned int)k;

    const float* Ur = U + (size_t)row * NN;
    const float* Dr = D + (size_t)row * NN;
    unsigned int* OrU = (unsigned int*)out + (size_t)row * NN;

    const unsigned int hi_u = ws[WS_HI + row];
    const unsigned int lo_u = ws[WS_LO + row];
    const int candCnt0 = ((int*)ws)[WS_CAND + row];
    const int A = ((int*)ws)[WS_A + row];
    const unsigned int* gk = ws + WS_KEYS + (size_t)row * CAPC;
    const int* gi = (const int*)ws + WS_IDX + (size_t)row * CAPC;

    __shared__ unsigned int hist[8192];
    __shared__ unsigned int chunkSum[NTC];
    __shared__ unsigned int candKey[CAPC];
    __shared__ int candIdx[CAPC];
    __shared__ unsigned int bandU[CAPB];
    __shared__ int bandIdxA[CAPB];
    __shared__ unsigned int s_sel, s_kneed, s_eq;
    __shared__ int s_bandCnt, s_above, s_tiecnt, s_tieidx;
    int* tielist = candIdx;

    const int kb = k - A;
    bool fb = (candCnt0 > CAPC) || (kb < 1) || (kb > candCnt0);
    const int candCnt = candCnt0 > CAPC ? CAPC : candCnt0;

    unsigned int theta_q = 0, band_lo_u = 0, band_hi_u = 0;
    if (!fb) {
        if (tid == 0) { s_bandCnt = 0; s_above = 0; }
        for (int j = tid; j < candCnt; j += NTC) { candKey[j] = gk[j]; candIdx[j] = gi[j]; }
        for (int i = tid; i < 8192; i += NTC) hist[i] = 0;
        __syncthreads();
        for (int j = tid; j < candCnt; j += NTC) atomicAdd(&hist[candKey[j] >> 19], 1u);
        __syncthreads();
        PASS1SEL((unsigned int)kb)
        const unsigned int c13 = s_sel; const unsigned int ck1 = s_kneed;
        hist[tid] = 0;
        __syncthreads();
        for (int j = tid; j < candCnt; j += NTC) { unsigned int ck = candKey[j];
            if ((ck >> 19) == c13) atomicAdd(&hist[(ck >> 9) & 1023u], 1u); }
        __syncthreads();
        PASS2SEL(c13, ck1)
        const unsigned int c23 = s_sel; const unsigned int ck2 = s_kneed;
        if (tid < 512) hist[tid] = 0;
        __syncthreads();
        for (int j = tid; j < candCnt; j += NTC) { unsigned int ck = candKey[j];
            if ((ck >> 9) == c23) atomicAdd(&hist[ck & 511u], 1u); }
        __syncthreads();
        PASS3SEL(c23, ck2)
        theta_q = s_sel;

        const float theta_f = sort2f(theta_q);
        band_lo_u = f2sort(theta_f * (1.0f - QMARG));
        band_hi_u = f2sort(theta_f * (1.0f + QMARG));
        { const unsigned int fl = (theta_q >= 0x80000100u) ? (theta_q - 256u) : 0x80000000u;
          if (band_lo_u > fl) band_lo_u = fl;
          const unsigned int fh = theta_q + 256u;
          if (band_hi_u < fh) band_hi_u = fh; }
        // margin zone must lie strictly inside (lo_pivot, hi_pivot]
        fb = !(finite_f(theta_f)) || !(band_hi_u < hi_u) || !(band_lo_u > lo_u);
    }

    if (!fb) {
        int ab = 0;
        for (int j = tid; j < candCnt; j += NTC) {
            const unsigned int ck = candKey[j];
            if (ck > band_hi_u) ab++;
            else if (ck >= band_lo_u) {
                const int slot = atomicAdd(&s_bandCnt, 1);
                if (slot < CAPB) bandIdxA[slot] = candIdx[j];
            }
        }
#pragma unroll
        for (int off = 32; off >= 1; off >>= 1) ab += __shfl_down(ab, off);
        if (lane == 0) atomicAdd(&s_above, ab);
        __syncthreads();
        const int bandCnt = s_bandCnt;
        const int kb2 = kb - s_above;
        fb = (bandCnt > CAPB) || (kb2 < 0) || (kb2 > bandCnt);

        if (!fb) {
            for (int j = tid; j < bandCnt; j += NTC) {
                const int idx = bandIdxA[j];
                bandU[j] = wexact(Ur[idx], Dr[idx]);
            }
            __syncthreads();
            for (int j = tid; j < bandCnt; j += NTC) {
                const unsigned int me = bandU[j];
                const int mi = bandIdxA[j];
                int rk = 0;
                for (int i = 0; i < bandCnt; i++) {
                    const unsigned int o = bandU[i];
                    rk += (int)((o > me) || (o == me && bandIdxA[i] < mi));
                }
                if (rk < kb2) OrU[mi] = ONE_BITS;
            }
            for (int j = tid; j < candCnt; j += NTC)
                if (candKey[j] > band_hi_u) OrU[candIdx[j]] = ONE_BITS;
            return;
        }
    }

    // ================= exact fallback (uniform branch; rare) =================
    __syncthreads();
    for (int i = tid; i < 8192; i += NTC) hist[i] = 0;
    __syncthreads();
#pragma unroll 1
    for (int J = 0; J < 16; ++J) {
        const int e = (J << 12) + (tid << 2);
        float4 u4 = *(const float4*)(Ur + e);
        float4 d4 = *(const float4*)(Dr + e);
        u32x4 kv;
        kv.x = wexact(u4.x, d4.x);
        kv.y = wexact(u4.y, d4.y);
        kv.z = wexact(u4.z, d4.z);
        kv.w = wexact(u4.w, d4.w);
        *(u32x4*)(OrU + e) = kv;
        atomicAdd(&hist[kv.x >> 19], 1u);
        atomicAdd(&hist[kv.y >> 19], 1u);
        atomicAdd(&hist[kv.z >> 19], 1u);
        atomicAdd(&hist[kv.w >> 19], 1u);
    }
    __syncthreads();

    PASS1SEL(kk)
    const unsigned int q13 = s_sel;
    const unsigned int en1 = s_kneed;
    hist[tid] = 0;
    __syncthreads();
#pragma unroll 1
    for (int J = 0; J < 16; ++J) {
        const int e = (J << 12) + (tid << 2);
        u32x4 kv = *(const u32x4*)(OrU + e);
        if ((kv.x >> 19) == q13) atomicAdd(&hist[(kv.x >> 9) & 1023u], 1u);
        if ((kv.y >> 19) == q13) atomicAdd(&hist[(kv.y >> 9) & 1023u], 1u);
        if ((kv.z >> 19) == q13) atomicAdd(&hist[(kv.z >> 9) & 1023u], 1u);
        if ((kv.w >> 19) == q13) atomicAdd(&hist[(kv.w >> 9) & 1023u], 1u);
    }
    __syncthreads();
    PASS2SEL(q13, en1)

    const unsigned int q23 = s_sel;
    const unsigned int en2 = s_kneed;
    if (tid < 512) hist[tid] = 0;
    __syncthreads();
#pragma unroll 1
    for (int J = 0; J < 16; ++J) {
        const int e = (J << 12) + (tid << 2);
        u32x4 kv = *(const u32x4*)(OrU + e);
        if ((kv.x >> 9) == q23) atomicAdd(&hist[kv.x & 511u], 1u);
        if ((kv.y >> 9) == q23) atomicAdd(&hist[kv.y & 511u], 1u);
        if ((kv.z >> 9) == q23) atomicAdd(&hist[kv.z & 511u], 1u);
        if ((kv.w >> 9) == q23) atomicAdd(&hist[kv.w & 511u], 1u);
    }
    __syncthreads();
    PASS3SEL(q23, en2)

    const unsigned int theta = s_sel;
    const unsigned int kneedF = s_kneed, eqF = s_eq;
    const bool needOrder = (kneedF < eqF);
    int istar = NN;
    if (needOrder) {
        if (tid == 0) s_tiecnt = 0;
        __syncthreads();
#pragma unroll 1
        for (int J = 0; J < 16; ++J) {
            const int e = (J << 12) + (tid << 2);
            u32x4 kv = *(const u32x4*)(OrU + e);
#define TIEV(UU, EIDX) if ((UU) == theta) { \
                int pos = atomicAdd(&s_tiecnt, 1); \
                if (pos < 1024) tielist[pos] = (EIDX); }
            TIEV(kv.x, e + 0)
            TIEV(kv.y, e + 1)
            TIEV(kv.z, e + 2)
            TIEV(kv.w, e + 3)
#undef TIEV
        }
        __syncthreads();
        if (tid == 0) {
            int E = s_tiecnt; if (E > 1024) E = 1024;
            for (int aI = 1; aI < E; aI++) {
                int val = tielist[aI]; int bI = aI - 1;
                while (bI >= 0 && tielist[bI] > val) { tielist[bI + 1] = tielist[bI]; bI--; }
                tielist[bI + 1] = val;
            }
            int kk2 = (int)kneedF; if (kk2 > E) kk2 = E; if (kk2 < 1) kk2 = 1;
            s_tieidx = tielist[kk2 - 1];
        }
        __syncthreads();
        istar = s_tieidx;
    }

#pragma unroll 1
    for (int J = 0; J < 16; ++J) {
        const int e = (J << 12) + (tid << 2);
        u32x4 kv = *(const u32x4*)(OrU + e);
        u32x4 m;
#define MVE(u, idx) ((((u) > theta) || ((u) == theta && (!needOrder || (idx) <= istar))) ? ONE_BITS : 0u)
        m.x = MVE(kv.x, e + 0);
        m.y = MVE(kv.y, e + 1);
        m.z = MVE(kv.z, e + 2);
        m.w = MVE(kv.w, e + 3);
#undef MVE
        *(u32x4*)(OrU + e) = m;
    }
}

// ============ R5 validated single-kernel (fallback if ws too small) ========
__global__ __launch_bounds__(NTC, 4)
void md_fused_kernel(const float* __restrict__ Tt,
                     const float* __restrict__ U,
                     const float* __restrict__ D,
                     float* __restrict__ out,
                     float* __restrict__ wout) {
    const int row = blockIdx.x;
    const int tid = threadIdx.x;
    const int lane = tid & 63;

    const float* Ur = U + (size_t)row * NN;
    const float* Dr = D + (size_t)row * NN;
    unsigned int* OrU = (unsigned int*)out + (size_t)row * NN;

    __shared__ unsigned int hist[8192];
    __shared__ unsigned int chunkSum[NTC];
    __shared__ unsigned int skey[SM];
    __shared__ unsigned int candKey[CAPC];
    __shared__ int candIdx[CAPC];
    __shared__ unsigned int s_sel, s_kneed, s_eq;
    __shared__ int s_A, s_candCnt, s_bandCnt, s_above, s_tiecnt, s_tieidx;

    unsigned int* bandU = skey;
    int* bandIdxA = (int*)(skey + CAPB);
    int* tielist = candIdx;

    const float t = Tt[row];
    const float pf = (float)M_PI;
    float bbv = (pf * t) * 0.5f;
    float c0 = (float)cos((double)bbv);
    const int k = (int)(65536.0f * (1.0f - c0));
    if (tid == 0) {
        float tadj = t * 0.998f + 0.001f;
        float arg  = (pf * tadj) * 0.5f;
        wout[row] = (float)(0.5 * M_PI) * (float)sin((double)arg);
    }

    if (k <= 0 || k >= NN) {
        const unsigned int fbv = (k >= NN) ? ONE_BITS : 0u;
        u32x4 f4 = {fbv, fbv, fbv, fbv};
        for (int j = 0; j < 16; j++)
            __builtin_nontemporal_store(f4, (u32x4*)(OrU + j * 4096 + tid * 4));
        return;
    }
    const unsigned int kk = (unsigned int)k;

    for (int i = tid; i < 8192; i += NTC) hist[i] = 0;
    if (tid == 0) { s_A = 0; s_candCnt = 0; s_bandCnt = 0; s_above = 0; }
    __syncthreads();
    {
        float4 u4 = *(const float4*)(Ur + (tid << 2));
        float4 d4 = *(const float4*)(Dr + (tid << 2));
        unsigned int s0 = qkey(u4.x, d4.x), s1 = qkey(u4.y, d4.y);
        unsigned int s2 = qkey(u4.z, d4.z), s3 = qkey(u4.w, d4.w);
        skey[(tid << 2) + 0] = s0; skey[(tid << 2) + 1] = s1;
        skey[(tid << 2) + 2] = s2; skey[(tid << 2) + 3] = s3;
        atomicAdd(&hist[s0 >> 19], 1u); atomicAdd(&hist[s1 >> 19], 1u);
        atomicAdd(&hist[s2 >> 19], 1u); atomicAdd(&hist[s3 >> 19], 1u);
    }
    __syncthreads();

    const int rh = (k >> 4) - RANKPAD;
    unsigned int hi_pivot_u = 0xFFFFFFFFu;
    if (rh >= 1) {
        PASS1SEL((unsigned int)rh)
        const unsigned int bh = s_sel; const unsigned int knh = s_kneed;
        hist[tid] = 0;
        __syncthreads();
        for (int j = tid; j < SM; j += NTC) { unsigned int sk = skey[j];
            if ((sk >> 19) == bh) atomicAdd(&hist[(sk >> 9) & 1023u], 1u); }
        __syncthreads();
        PASS2SEL(bh, knh)
        hi_pivot_u = (s_sel << 9) | 0x1FFu;
        for (int i = tid; i < 8192; i += NTC) hist[i] = 0;
        __syncthreads();
        for (int j = tid; j < SM; j += NTC) atomicAdd(&hist[skey[j] >> 19], 1u);
        __syncthreads();
    }

    const int rl = ((k + 15) >> 4) + RANKPAD;
    unsigned int lo_pivot_u = 0u;
    if (rl <= SM) {
        PASS1SEL((unsigned int)rl)
        const unsigned int bl = s_sel; const unsigned int knl = s_kneed;
        hist[tid] = 0;
        __syncthreads();
        for (int j = tid; j < SM; j += NTC) { unsigned int sk = skey[j];
            if ((sk >> 19) == bl) atomicAdd(&hist[(sk >> 9) & 1023u], 1u); }
        __syncthreads();
        PASS2SEL(bl, knl)
        lo_pivot_u = (s_sel << 9);
    }
    __syncthreads();

    {
        int cntA = 0;
#pragma unroll 2
        for (int J = 0; J < 16; ++J) {
            const int e = (J << 12) + (tid << 2);
            float4 u4 = *(const float4*)(Ur + e);
            float4 d4 = *(const float4*)(Dr + e);
            u32x4 kv;
            kv.x = qkey(u4.x, d4.x); kv.y = qkey(u4.y, d4.y);
            kv.z = qkey(u4.z, d4.z); kv.w = qkey(u4.w, d4.w);
            u32x4 m;
#define MPROC(KC, CI, MF) { \
            const unsigned int qv = (KC); \
            const bool din = qv > hi_pivot_u; \
            cntA += (int)din; MF = din ? ONE_BITS : 0u; \
            if (!din && qv > lo_pivot_u) { \
                int slot = atomicAdd(&s_candCnt, 1); \
                if (slot < CAPC) { candKey[slot] = qv; candIdx[slot] = e + (CI); } } }
            MPROC(kv.x, 0, m.x)
            MPROC(kv.y, 1, m.y)
            MPROC(kv.z, 2, m.z)
            MPROC(kv.w, 3, m.w)
#undef MPROC
            *(u32x4*)(OrU + e) = m;
        }
#pragma unroll
        for (int off = 32; off >= 1; off >>= 1) cntA += __shfl_down(cntA, off);
        if (lane == 0) atomicAdd(&s_A, cntA);
    }
    __syncthreads();

    const int candCnt0 = s_candCnt;
    const int candCnt = candCnt0 > CAPC ? CAPC : candCnt0;
    const int kb = k - s_A;
    bool fb = (candCnt0 > CAPC) || (kb < 1) || (kb > candCnt0);

    unsigned int theta_q = 0, band_lo_u = 0, band_hi_u = 0;
    if (!fb) {
        for (int i = tid; i < 8192; i += NTC) hist[i] = 0;
        __syncthreads();
        for (int j = tid; j < candCnt; j += NTC) atomicAdd(&hist[candKey[j] >> 19], 1u);
        __syncthreads();
        PASS1SEL((unsigned int)kb)
        const unsigned int c13 = s_sel; const unsigned int ck1 = s_kneed;
        hist[tid] = 0;
        __syncthreads();
        for (int j = tid; j < candCnt; j += NTC) { unsigned int ck = candKey[j];
            if ((ck >> 19) == c13) atomicAdd(&hist[(ck >> 9) & 1023u], 1u); }
        __syncthreads();
        PASS2SEL(c13, ck1)
        const unsigned int c23 = s_sel; const unsigned int ck2 = s_kneed;
        if (tid < 512) hist[tid] = 0;
        __syncthreads();
        for (int j = tid; j < candCnt; j += NTC) { unsigned int ck = candKey[j];
            if ((ck >> 9) == c23) atomicAdd(&hist[ck & 511u], 1u); }
        __syncthreads();
        PASS3SEL(c23, ck2)
        theta_q = s_sel;

        const float theta_f = sort2f(theta_q);
        band_lo_u = f2sort(theta_f * (1.0f - QMARG));
        band_hi_u = f2sort(theta_f * (1.0f + QMARG));
        { const unsigned int fl = (theta_q >= 0x80000100u) ? (theta_q - 256u) : 0x80000000u;
          if (band_lo_u > fl) band_lo_u = fl;
          const unsigned int fh = theta_q + 256u;
          if (band_hi_u < fh) band_hi_u = fh; }
        fb = !(finite_f(theta_f)) || !(band_hi_u < hi_pivot_u) || !(band_lo_u > lo_pivot_u);
    }

    if (!fb) {
        int ab = 0;
        for (int j = tid; j < candCnt; j += NTC) {
            const unsigned int ck = candKey[j];
            if (ck > band_hi_u) ab++;
            else if (ck >= band_lo_u) {
                const int slot = atomicAdd(&s_bandCnt, 1);
                if (slot < CAPB) bandIdxA[slot] = candIdx[j];
            }
        }
#pragma unroll
        for (int off = 32; off >= 1; off >>= 1) ab += __shfl_down(ab, off);
        if (lane == 0) atomicAdd(&s_above, ab);
        __syncthreads();
        const int bandCnt = s_bandCnt;
        const int kb2 = kb - s_above;
        fb = (bandCnt > CAPB) || (kb2 < 0) || (kb2 > bandCnt);

        if (!fb) {
            for (int j = tid; j < bandCnt; j += NTC) {
                const int idx = bandIdxA[j];
                bandU[j] = wexact(Ur[idx], Dr[idx]);
            }
            __syncthreads();
            for (int j = tid; j < bandCnt; j += NTC) {
                const unsigned int me = bandU[j];
                const int mi = bandIdxA[j];
                int rk = 0;
                for (int i = 0; i < bandCnt; i++) {
                    const unsigned int o = bandU[i];
                    rk += (int)((o > me) || (o == me && bandIdxA[i] < mi));
                }
                if (rk < kb2) OrU[mi] = ONE_BITS;
            }
            for (int j = tid; j < candCnt; j += NTC)
                if (candKey[j] > band_hi_u) OrU[candIdx[j]] = ONE_BITS;
            return;
        }
    }

    __syncthreads();
    for (int i = tid; i < 8192; i += NTC) hist[i] = 0;
    __syncthreads();
#pragma unroll 1
    for (int J = 0; J < 16; ++J) {
        const int e = (J << 12) + (tid << 2);
        float4 u4 = *(const float4*)(Ur + e);
        float4 d4 = *(const float4*)(Dr + e);
        u32x4 kv;
        kv.x = wexact(u4.x, d4.x);
        kv.y = wexact(u4.y, d4.y);
        kv.z = wexact(u4.z, d4.z);
        kv.w = wexact(u4.w, d4.w);
        *(u32x4*)(OrU + e) = kv;
        atomicAdd(&hist[kv.x >> 19], 1u);
        atomicAdd(&hist[kv.y >> 19], 1u);
        atomicAdd(&hist[kv.z >> 19], 1u);
        atomicAdd(&hist[kv.w >> 19], 1u);
    }
    __syncthreads();

    PASS1SEL(kk)
    const unsigned int q13 = s_sel;
    const unsigned int en1 = s_kneed;
    hist[tid] = 0;
    __syncthreads();
#pragma unroll 1
    for (int J = 0; J < 16; ++J) {
        const int e = (J << 12) + (tid << 2);
        u32x4 kv = *(const u32x4*)(OrU + e);
        if ((kv.x >> 19) == q13) atomicAdd(&hist[(kv.x >> 9) & 1023u], 1u);
        if ((kv.y >> 19) == q13) atomicAdd(&hist[(kv.y >> 9) & 1023u], 1u);
        if ((kv.z >> 19) == q13) atomicAdd(&hist[(kv.z >> 9) & 1023u], 1u);
        if ((kv.w >> 19) == q13) atomicAdd(&hist[(kv.w >> 9) & 1023u], 1u);
    }
    __syncthreads();
    PASS2SEL(q13, en1)

    const unsigned int q23 = s_sel;
    const unsigned int en2 = s_kneed;
    if (tid < 512) hist[tid] = 0;
    __syncthreads();
#pragma unroll 1
    for (int J = 0; J < 16; ++J) {
        const int e = (J << 12) + (tid << 2);
        u32x4 kv = *(const u32x4*)(OrU + e);
        if ((kv.x >> 9) == q23) atomicAdd(&hist[kv.x & 511u], 1u);
        if ((kv.y >> 9) == q23) atomicAdd(&hist[kv.y & 511u], 1u);
        if ((kv.z >> 9) == q23) atomicAdd(&hist[kv.z & 511u], 1u);
        if ((kv.w >> 9) == q23) atomicAdd(&hist[kv.w & 511u], 1u);
    }
    __syncthreads();
    PASS3SEL(q23, en2)

    const unsigned int theta = s_sel;
    const unsigned int kneedF = s_kneed, eqF = s_eq;
    const bool needOrder = (kneedF < eqF);
    int istar = NN;
    if (needOrder) {
        if (tid == 0) s_tiecnt = 0;
        __syncthreads();
#pragma unroll 1
        for (int J = 0; J < 16; ++J) {
            const int e = (J << 12) + (tid << 2);
            u32x4 kv = *(const u32x4*)(OrU + e);
#define TIEV(UU, EIDX) if ((UU) == theta) { \
                int pos = atomicAdd(&s_tiecnt, 1); \
                if (pos < 1024) tielist[pos] = (EIDX); }
            TIEV(kv.x, e + 0)
            TIEV(kv.y, e + 1)
            TIEV(kv.z, e + 2)
            TIEV(kv.w, e + 3)
#undef TIEV
        }
        __syncthreads();
        if (tid == 0) {
            int E = s_tiecnt; if (E > 1024) E = 1024;
            for (int aI = 1; aI < E; aI++) {
                int val = tielist[aI]; int bI = aI - 1;
                while (bI >= 0 && tielist[bI] > val) { tielist[bI + 1] = tielist[bI]; bI--; }
                tielist[bI + 1] = val;
            }
            int kk2 = (int)kneedF; if (kk2 > E) kk2 = E; if (kk2 < 1) kk2 = 1;
            s_tieidx = tielist[kk2 - 1];
        }
        __syncthreads();
        istar = s_tieidx;
    }

#pragma unroll 1
    for (int J = 0; J < 16; ++J) {
        const int e = (J << 12) + (tid << 2);
        u32x4 kv = *(const u32x4*)(OrU + e);
        u32x4 m;
#define MVE(u, idx) ((((u) > theta) || ((u) == theta && (!needOrder || (idx) <= istar))) ? ONE_BITS : 0u)
        m.x = MVE(kv.x, e + 0);
        m.y = MVE(kv.y, e + 1);
        m.z = MVE(kv.z, e + 2);
        m.w = MVE(kv.w, e + 3);
#undef MVE
        *(u32x4*)(OrU + e) = m;
    }
}

extern "C" void kernel_launch(void* const* d_in, const int* in_sizes, int n_in,
                              void* d_out, int out_size, void* d_ws, size_t ws_size,
                              hipStream_t stream) {
    // inputs: batch[B*N] i32 (unused), t[B] f32, U[B*N] f32, D[B*N] f32
    const float* T = (const float*)d_in[1];
    const float* U = (const float*)d_in[2];
    const float* D = (const float*)d_in[3];
    float* out = (float*)d_out;
    float* wout = out + (size_t)BB * NN;

    if (d_ws != nullptr && ws_size >= WS_WORDS * 4ull) {
        unsigned int* ws = (unsigned int*)d_ws;
        md_pivots<<<BB, NTA, 0, stream>>>(T, U, D, ws, wout);
        md_stream<<<BB * SLICES, NTB, 0, stream>>>(U, D, out, ws);
        md_select<<<BB, NTC, 0, stream>>>(U, D, out, ws);
    } else {
        md_fused_kernel<<<BB, NTC, 0, stream>>>(T, U, D, out, wout);
    }
}